// Round 13
// baseline (42.515 us; speedup 1.0000x reference)
//
#include <hip/hip_runtime.h>

#define NBATCH 4
#define NPTS   4096
#define XPT    8                  // x-points per thread
#define XCHUNK 2048               // 256 threads * XPT
#define NXC    2                  // x-chunks per (dir,b)
#define YCHUNK 128
#define NYC    32                 // y-chunks per (dir,b)
#define NBLK   512                // NXC*NYC*8
#define BIGF   1e30f

#define LOAD_AG(p)    __hip_atomic_load((p),  __ATOMIC_RELAXED, __HIP_MEMORY_SCOPE_AGENT)
#define STORE_AG(p,v) __hip_atomic_store((p),(v), __ATOMIC_RELAXED, __HIP_MEMORY_SCOPE_AGENT)

// Single-dispatch chamfer loss, 3 layers:
//  producers (all 512 blocks): R6-geometry partial mins (XPT=8, YCHUNK=128,
//    1/8 ds_read per pair), agent-scope stores to partial, release flag1.
//  reducers (16 blocks, yc==0): spin on their (xc,zc) group's 32 flag1s,
//    min over 32 rows per x, mask dir-1, block-sum -> rsum + flag2,
//    reset the 32 flag1s (sole owner).
//  finalizer (block 0): spin 16 flag2s, sum rsum -> out[0], reset flag2.
// Deadlock-free: producers never wait; 16 spinners << residency capacity.
// Self-cleaning: flags reset to 0 each call; any initial value != 1 is safe
// (0xAA poison / 0). partial & rsum are written-before-read every call.
__global__ __launch_bounds__(256)
void chamfer_fused_kernel(const float* __restrict__ preds,
                          const float* __restrict__ gts,
                          const int* __restrict__ mask,
                          float* __restrict__ partial,   // [8][NYC][NPTS]
                          float* __restrict__ rsum,      // [16]
                          unsigned* __restrict__ flag1,  // [512]
                          unsigned* __restrict__ flag2,  // [16]
                          float* __restrict__ out) {
    const int bid = blockIdx.x;
    const int tid = threadIdx.x;
    const int xc  = bid & 1;
    const int yc  = (bid >> 1) & 31;
    const int zc  = bid >> 6;          // dir*4 + b
    const int dir = zc >> 2;
    const int b   = zc & 3;

    const float* X = (dir == 0 ? preds : gts) + (size_t)b * NPTS * 3;
    const float* Y = (dir == 0 ? gts : preds) + (size_t)b * NPTS * 3;

    // ---------------- producer ----------------
    __shared__ float4 sy[YCHUNK];
    if (tid < YCHUNK) {
        const int j = yc * YCHUNK + tid;
        const float y0 = Y[j * 3 + 0];
        const float y1 = Y[j * 3 + 1];
        const float y2 = Y[j * 3 + 2];
        float ry = y0 * y0 + y1 * y1 + y2 * y2;
        if (dir == 0 && mask[b * NPTS + j] == 0) ry = BIGF;
        sy[tid] = make_float4(y0, y1, y2, ry);
    }

    float a0[XPT], a1[XPT], a2[XPT], rx[XPT], m[XPT];
    const int xbase = xc * XCHUNK + tid;
    #pragma unroll
    for (int i = 0; i < XPT; ++i) {
        const int x = xbase + i * 256;
        float v0 = X[x * 3 + 0], v1 = X[x * 3 + 1], v2 = X[x * 3 + 2];
        rx[i] = v0 * v0 + v1 * v1 + v2 * v2;
        a0[i] = -2.0f * v0; a1[i] = -2.0f * v1; a2[i] = -2.0f * v2;
        m[i] = BIGF;
    }
    __syncthreads();

    #pragma unroll 2
    for (int k = 0; k < YCHUNK; k += 4) {
        const float4 p0 = sy[k + 0];
        const float4 p1 = sy[k + 1];
        const float4 p2 = sy[k + 2];
        const float4 p3 = sy[k + 3];
        #pragma unroll
        for (int i = 0; i < XPT; ++i) {
            const float t0 = fmaf(a0[i], p0.x, fmaf(a1[i], p0.y, fmaf(a2[i], p0.z, p0.w)));
            const float t1 = fmaf(a0[i], p1.x, fmaf(a1[i], p1.y, fmaf(a2[i], p1.z, p1.w)));
            const float t2 = fmaf(a0[i], p2.x, fmaf(a1[i], p2.y, fmaf(a2[i], p2.z, p2.w)));
            const float t3 = fmaf(a0[i], p3.x, fmaf(a1[i], p3.y, fmaf(a2[i], p3.z, p3.w)));
            m[i] = fminf(fminf(m[i], t0), t1);   // -> v_min3_f32
            m[i] = fminf(fminf(m[i], t2), t3);   // -> v_min3_f32
        }
    }

    {   // agent-scope stores: device-visible without L2 flush (R12-proven pattern)
        float* prow = partial + ((size_t)zc * NYC + yc) * NPTS + xbase;
        #pragma unroll
        for (int i = 0; i < XPT; ++i)
            STORE_AG(prow + i * 256, rx[i] + m[i]);
    }
    __syncthreads();   // all threads' stores issued before the flag
    if (tid == 0)
        __hip_atomic_store(&flag1[bid], 1u, __ATOMIC_RELEASE,
                           __HIP_MEMORY_SCOPE_AGENT);

    // ---------------- reducer (yc==0 blocks; 16 total) ----------------
    if (yc == 0) {
        if (tid < NYC) {
            // flag of (xc, y=tid, zc) is bid + 2*tid
            while (LOAD_AG(&flag1[bid + 2 * tid]) != 1u)
                __builtin_amdgcn_s_sleep(8);
        }
        __syncthreads();
        __threadfence();   // one acquire-side fence for the partial reads

        float acc = 0.0f;
        #pragma unroll
        for (int i = 0; i < XPT; ++i) {
            const int x = xbase + i * 256;
            const float* col = partial + (size_t)zc * NYC * NPTS + x;
            float mm = LOAD_AG(col);
            #pragma unroll
            for (int r = 1; r < NYC; ++r)
                mm = fminf(mm, LOAD_AG(col + (size_t)r * NPTS));
            float v = mm;
            if (dir == 1 && mask[b * NPTS + x] == 0) v = 0.0f;
            acc += v;
        }
        #pragma unroll
        for (int off = 32; off > 0; off >>= 1)
            acc += __shfl_down(acc, off, 64);

        __shared__ float ws4[4];
        if ((tid & 63) == 0) ws4[tid >> 6] = acc;
        __syncthreads();

        const int ridx = zc * 2 + xc;   // 0..15
        if (tid == 0) {
            STORE_AG(&rsum[ridx], ws4[0] + ws4[1] + ws4[2] + ws4[3]);
            __hip_atomic_store(&flag2[ridx], 1u, __ATOMIC_RELEASE,
                               __HIP_MEMORY_SCOPE_AGENT);
        }
        // sole owner of this group's flag1s: reset for the next call
        if (tid < NYC)
            STORE_AG(&flag1[bid + 2 * tid], 0u);
    }

    // ---------------- finalizer (block 0) ----------------
    if (bid == 0) {
        float v = 0.0f;
        if (tid < 16) {
            while (LOAD_AG(&flag2[tid]) != 1u)
                __builtin_amdgcn_s_sleep(8);
            v = LOAD_AG(&rsum[tid]);
        }
        #pragma unroll
        for (int off = 8; off > 0; off >>= 1)
            v += __shfl_down(v, off, 16);
        if (tid == 0) out[0] = v;
        if (tid < 16) STORE_AG(&flag2[tid], 0u);
    }
}

extern "C" void kernel_launch(void* const* d_in, const int* in_sizes, int n_in,
                              void* d_out, int out_size, void* d_ws, size_t ws_size,
                              hipStream_t stream) {
    const float* preds = (const float*)d_in[0];  // [B, Npred, 3]
    const float* gts   = (const float*)d_in[1];  // [B, Ngt, 3]
    const int*   mask  = (const int*)d_in[2];    // [B, Ngt]
    float* out = (float*)d_out;

    float*    partial = (float*)d_ws;                         // 4 MB
    float*    rsum    = partial + (size_t)8 * NYC * NPTS;     // [16]
    unsigned* flag1   = (unsigned*)(rsum + 16);               // [512]
    unsigned* flag2   = flag1 + NBLK;                         // [16]

    chamfer_fused_kernel<<<NBLK, 256, 0, stream>>>(
        preds, gts, mask, partial, rsum, flag1, flag2, out);
}

// Round 14
// 21.312 us; speedup vs baseline: 1.9948x; 1.9948x over previous
//
#include <hip/hip_runtime.h>

#define NBATCH 4
#define NPTS   4096
#define XPT    8                  // x-points per thread
#define XCHUNK (256 * XPT)        // 2048
#define NXC    (NPTS / XCHUNK)    // 2
#define YCHUNK 128                // y-points per block (64 pairs)
#define NPAIR  (YCHUNK / 2)       // 64
#define NYC    (NPTS / YCHUNK)    // 32
#define BIGF   1e30f

typedef float v2f __attribute__((ext_vector_type(2)));

// Kernel 1: partial mins with packed-f32 math.
// grid = (NXC, NYC, 2*NBATCH) = 512 blocks; block = 256.
// LDS pair layout per y-pair j: E0=(x_a,x_b,y_a,y_b), E1=(z_a,z_b,ry_a,ry_b)
// -> inner step per x: 3 v_pk_fma_f32 + 1 v_min3_f32 for TWO y (2 instr/pair).
__global__ __launch_bounds__(256)
void chamfer_min_kernel(const float* __restrict__ preds,
                        const float* __restrict__ gts,
                        const int* __restrict__ mask,
                        float* __restrict__ partial,
                        float* __restrict__ out) {
    const int zc  = blockIdx.z;
    const int dir = zc >> 2;
    const int b   = zc & 3;
    const int tid = threadIdx.x;

    // zero the output scalar exactly once (kernel2 accumulates after boundary)
    if ((zc | blockIdx.x | blockIdx.y | tid) == 0) out[0] = 0.0f;

    const float* X = (dir == 0 ? preds : gts) + (size_t)b * NPTS * 3;
    const float* Y = (dir == 0 ? gts : preds) + (size_t)b * NPTS * 3;

    __shared__ float4 sp[2 * NPAIR];   // 2 KB
    const int cbase = blockIdx.y * YCHUNK;
    if (tid < NPAIR) {
        const int ja = cbase + 2 * tid;
        const int jb = ja + 1;
        const float xa = Y[ja * 3 + 0], ya = Y[ja * 3 + 1], za = Y[ja * 3 + 2];
        const float xb = Y[jb * 3 + 0], yb = Y[jb * 3 + 1], zb = Y[jb * 3 + 2];
        float ra = xa * xa + ya * ya + za * za;
        float rb = xb * xb + yb * yb + zb * zb;
        if (dir == 0) {
            if (mask[b * NPTS + ja] == 0) ra = BIGF;
            if (mask[b * NPTS + jb] == 0) rb = BIGF;
        }
        sp[2 * tid + 0] = make_float4(xa, xb, ya, yb);
        sp[2 * tid + 1] = make_float4(za, zb, ra, rb);
    }

    // load XPT x-points; hoist packed splats of (-2x) out of the y-loop
    v2f A0[XPT], A1[XPT], A2[XPT];
    float rx[XPT], m[XPT];
    const int xbase = blockIdx.x * XCHUNK + tid;
    #pragma unroll
    for (int i = 0; i < XPT; ++i) {
        const int x = xbase + i * 256;
        const float v0 = X[x * 3 + 0], v1 = X[x * 3 + 1], v2 = X[x * 3 + 2];
        rx[i] = v0 * v0 + v1 * v1 + v2 * v2;
        const float s0 = -2.0f * v0, s1 = -2.0f * v1, s2 = -2.0f * v2;
        A0[i] = (v2f){s0, s0}; A1[i] = (v2f){s1, s1}; A2[i] = (v2f){s2, s2};
        m[i] = BIGF;
    }
    __syncthreads();

    #pragma unroll 2
    for (int j = 0; j < NPAIR; ++j) {
        const float4 E0 = sp[2 * j + 0];   // (x_a,x_b,y_a,y_b) broadcast
        const float4 E1 = sp[2 * j + 1];   // (z_a,z_b,ra,rb)
        const v2f X2 = (v2f){E0.x, E0.y};
        const v2f Y2 = (v2f){E0.z, E0.w};
        const v2f Z2 = (v2f){E1.x, E1.y};
        const v2f R2 = (v2f){E1.z, E1.w};
        #pragma unroll
        for (int i = 0; i < XPT; ++i) {
            // t = R2 + A2*Z2 + A1*Y2 + A0*X2  (3 x v_pk_fma_f32)
            v2f t = __builtin_elementwise_fma(A2[i], Z2, R2);
            t = __builtin_elementwise_fma(A1[i], Y2, t);
            t = __builtin_elementwise_fma(A0[i], X2, t);
            m[i] = fminf(fminf(m[i], t.x), t.y);   // -> v_min3_f32
        }
    }

    float* prow = partial + ((size_t)zc * NYC + blockIdx.y) * NPTS + xbase;
    #pragma unroll
    for (int i = 0; i < XPT; ++i)
        prow[i * 256] = rx[i] + m[i];
}

// Kernel 2: per point min over NYC=32 rows (float4: 4 points/thread,
// 32 independent vector loads), mask dir-1, sum -> atomicAdd(out).
// grid = 32768/4/256 = 32 blocks.
__global__ __launch_bounds__(256)
void chamfer_reduce_kernel(const float* __restrict__ partial,
                           const int* __restrict__ mask,
                           float* __restrict__ out) {
    const int gid = blockIdx.x * blockDim.x + threadIdx.x;
    const int p4  = gid * 4;            // first of 4 consecutive points
    const int dir = p4 >> 14;
    const int b   = (p4 >> 12) & 3;
    const int x   = p4 & 4095;
    const int zc  = dir * NBATCH + b;

    const float4* base = (const float4*)(partial + (size_t)zc * NYC * NPTS + x);
    float4 m4 = base[0];
    #pragma unroll
    for (int r = 1; r < NYC; ++r) {
        const float4 v = base[(size_t)r * (NPTS / 4)];
        m4.x = fminf(m4.x, v.x); m4.y = fminf(m4.y, v.y);
        m4.z = fminf(m4.z, v.z); m4.w = fminf(m4.w, v.w);
    }

    float acc;
    if (dir == 1) {
        const int4 mk = *(const int4*)(mask + b * NPTS + x);
        acc = (mk.x ? m4.x : 0.0f) + (mk.y ? m4.y : 0.0f)
            + (mk.z ? m4.z : 0.0f) + (mk.w ? m4.w : 0.0f);
    } else {
        acc = m4.x + m4.y + m4.z + m4.w;
    }

    #pragma unroll
    for (int off = 32; off > 0; off >>= 1)
        acc += __shfl_down(acc, off, 64);

    __shared__ float wsum[4];
    if ((threadIdx.x & 63) == 0) wsum[threadIdx.x >> 6] = acc;
    __syncthreads();
    if (threadIdx.x == 0)
        atomicAdd(out, wsum[0] + wsum[1] + wsum[2] + wsum[3]);
}

extern "C" void kernel_launch(void* const* d_in, const int* in_sizes, int n_in,
                              void* d_out, int out_size, void* d_ws, size_t ws_size,
                              hipStream_t stream) {
    const float* preds = (const float*)d_in[0];  // [B, Npred, 3]
    const float* gts   = (const float*)d_in[1];  // [B, Ngt, 3]
    const int*   mask  = (const int*)d_in[2];    // [B, Ngt]
    float* out = (float*)d_out;

    float* partial = (float*)d_ws;  // [8][NYC][NPTS] = 4 MB

    dim3 grid(NXC, NYC, 2 * NBATCH);
    chamfer_min_kernel<<<grid, 256, 0, stream>>>(preds, gts, mask, partial, out);

    chamfer_reduce_kernel<<<(2 * NBATCH * NPTS / 4) / 256, 256, 0, stream>>>(
        partial, mask, out);
}